// Round 4
// baseline (429.838 us; speedup 1.0000x reference)
//
#include <hip/hip_runtime.h>

typedef __bf16 bf16_t;
typedef __bf16 bf16x8 __attribute__((ext_vector_type(8)));
typedef float f32x4 __attribute__((ext_vector_type(4)));

#define MFMA16(a, b, c) __builtin_amdgcn_mfma_f32_16x16x32_bf16((a), (b), (c), 0, 0, 0)

// ---------------------------------------------------------------------------
// Runtime dtype probe: for fp32 N(0,1) data the even uint16 halves are
// mantissa bits (uniform exponent field); for bf16 data they are real bf16
// values with exponent in [0x70,0x8F]. Count in-band among 32 even halves.
// ---------------------------------------------------------------------------
__global__ void dtype_probe(const unsigned short* __restrict__ hs,
                            int* __restrict__ flag) {
    if (threadIdx.x == 0) {
        int cnt = 0;
        for (int i = 0; i < 64; i += 2) {
            const int e = (hs[i] >> 7) & 0xFF;
            cnt += (e >= 0x70 && e <= 0x8F) ? 1 : 0;
        }
        *flag = (cnt >= 24) ? 1 : 0;  // 1 = inputs are bf16, 0 = fp32
    }
}

__device__ inline bf16x8 cvt8(const float* p) {
    const f32x4 a = *(const f32x4*)p;
    const f32x4 b = *(const f32x4*)(p + 4);
    bf16x8 r;
#pragma unroll
    for (int i = 0; i < 4; i++) { r[i] = (bf16_t)a[i]; r[4 + i] = (bf16_t)b[i]; }
    return r;
}

__device__ inline bf16x8 load8d(const void* base, size_t eoff, bool isbf) {
    if (isbf) return *(const bf16x8*)((const bf16_t*)base + eoff);
    return cvt8((const float*)base + eoff);
}

// ---------------------------------------------------------------------------
// GEMM: C[M x N] = A[M x K] * B[N x K]^T,  K = 1024, fp32-or-bf16 in, fp32 acc.
// 128x128 tile, BK=32, 256 threads (4 waves), each wave 64x64 = 4x4 MFMA tiles.
// Register staging: load -> cvt bf16 -> LDS store (m92 structure).
// ABF: A is always bf16 (internal ctx workspace), ignore flag for A.
// MODE 0: store C row-major to outp (bf16 or fp32 per flag), N = NDIM
// MODE 1: qkv scatter epilogue: m = b*2048+t, n = j*64+d
//         j<16 -> q_ws[bh][t][d]; j<32 -> k_ws[bh][t][d]; else v_ws[bh][d][t]
// ---------------------------------------------------------------------------
template <int MODE, int NDIM, bool ABF>
__global__ __launch_bounds__(256) void gemm_bt(const void* __restrict__ A,
                                               const void* __restrict__ B,
                                               void* __restrict__ outp,
                                               bf16_t* __restrict__ q_ws,
                                               bf16_t* __restrict__ k_ws,
                                               bf16_t* __restrict__ v_ws,
                                               const int* __restrict__ flag) {
    constexpr int K = 1024;
    __shared__ __align__(16) bf16_t As[128 * 32];
    __shared__ __align__(16) bf16_t Bs[128 * 32];

    const bool isbf = (*flag != 0);

    const int tid = threadIdx.x;
    const int w = tid >> 6;
    const int lane = tid & 63;
    const int lr = lane & 15;
    const int quad = lane >> 4;
    const int m0 = blockIdx.y * 128;
    const int n0 = blockIdx.x * 128;
    const int wm = (w & 1) * 64;
    const int wn = (w >> 1) * 64;

    // staging map: thread tid covers tile rows {srow, srow+64}, k-chunk skk..skk+8
    const int srow = tid >> 2;
    const int skk = (tid & 3) * 8;
    const size_t aoff = (size_t)(m0 + srow) * K + skk;
    const size_t boff = (size_t)(n0 + srow) * K + skk;

    f32x4 acc[4][4] = {};

    for (int k0 = 0; k0 < K; k0 += 32) {
        const bf16x8 ra0 = load8d(A, aoff + k0, ABF || isbf);
        const bf16x8 ra1 = load8d(A, aoff + (size_t)64 * K + k0, ABF || isbf);
        const bf16x8 rb0 = load8d(B, boff + k0, isbf);
        const bf16x8 rb1 = load8d(B, boff + (size_t)64 * K + k0, isbf);
        __syncthreads();  // previous iteration done reading LDS
        *(bf16x8*)&As[srow * 32 + skk] = ra0;
        *(bf16x8*)&As[(64 + srow) * 32 + skk] = ra1;
        *(bf16x8*)&Bs[srow * 32 + skk] = rb0;
        *(bf16x8*)&Bs[(64 + srow) * 32 + skk] = rb1;
        __syncthreads();  // LDS tile ready

        bf16x8 af[4], bfm[4];
#pragma unroll
        for (int im = 0; im < 4; im++)
            af[im] = *(const bf16x8*)&As[(wm + im * 16 + lr) * 32 + quad * 8];
#pragma unroll
        for (int in = 0; in < 4; in++)
            bfm[in] = *(const bf16x8*)&Bs[(wn + in * 16 + lr) * 32 + quad * 8];
#pragma unroll
        for (int im = 0; im < 4; im++)
#pragma unroll
            for (int in = 0; in < 4; in++)
                acc[im][in] = MFMA16(af[im], bfm[in], acc[im][in]);
    }

#pragma unroll
    for (int im = 0; im < 4; im++) {
#pragma unroll
        for (int in = 0; in < 4; in++) {
#pragma unroll
            for (int r = 0; r < 4; r++) {
                const int m = m0 + wm + im * 16 + quad * 4 + r;
                const int n = n0 + wn + in * 16 + lr;
                const float v = acc[im][in][r];
                if constexpr (MODE == 0) {
                    if (isbf) ((bf16_t*)outp)[(size_t)m * NDIM + n] = (bf16_t)v;
                    else      ((float*)outp)[(size_t)m * NDIM + n] = v;
                } else {
                    const int b = m >> 11;      // T = 2048
                    const int t = m & 2047;
                    const int j = n >> 6;       // which of 48 head-slots
                    const int d = n & 63;
                    if (j < 16) {
                        q_ws[(((size_t)(b * 16 + j) * 2048) + t) * 64 + d] = (bf16_t)v;
                    } else if (j < 32) {
                        k_ws[(((size_t)(b * 16 + (j - 16)) * 2048) + t) * 64 + d] = (bf16_t)v;
                    } else {
                        v_ws[((size_t)(b * 16 + (j - 32)) * 64 + d) * 2048 + t] = (bf16_t)v;
                    }
                }
            }
        }
    }
}

// ---------------------------------------------------------------------------
// RoPE in place on q_ws, k_ws ([bh][t][64] bf16). Pairs (d, d+32).
// cos/sin dtype per flag. Folds the 1/sqrt(D) = 0.125 scale into q.
// idx bits: d[0:5) t[5:16) bh[16:21) isk[21]
// ---------------------------------------------------------------------------
__global__ __launch_bounds__(256) void rope_kernel(bf16_t* __restrict__ q_ws,
                                                   bf16_t* __restrict__ k_ws,
                                                   const void* __restrict__ cosb,
                                                   const void* __restrict__ sinb,
                                                   const int* __restrict__ flag) {
    const bool isbf = (*flag != 0);
    const int idx = blockIdx.x * 256 + threadIdx.x;
    const int d = idx & 31;
    const int t = (idx >> 5) & 2047;
    const int bh = (idx >> 16) & 31;
    const int isk = idx >> 21;
    bf16_t* p = isk ? k_ws : q_ws;
    const size_t base = ((size_t)bh * 2048 + t) * 64;
    const float x1 = (float)p[base + d];
    const float x2 = (float)p[base + d + 32];
    const int ci = t * 64 + d;
    const float c = isbf ? (float)((const bf16_t*)cosb)[ci] : ((const float*)cosb)[ci];
    const float s = isbf ? (float)((const bf16_t*)sinb)[ci] : ((const float*)sinb)[ci];
    float y1 = x1 * c - x2 * s;
    float y2 = x2 * c + x1 * s;
    if (!isk) { y1 *= 0.125f; y2 *= 0.125f; }
    p[base + d] = (bf16_t)y1;
    p[base + d + 32] = (bf16_t)y2;
}

// ---------------------------------------------------------------------------
// Flash attention (bf16 ws in/out; dtype-independent). Grid: bh(32) x qtile(32).
// 256 threads = 4 waves; wave w owns Q rows [t0+16w, t0+16w+16).
// Per 32-key block: S = Q K^T, causal mask, online softmax (16-lane shfl),
// P -> LDS -> A-layout, PV MFMA.
// ---------------------------------------------------------------------------
__global__ __launch_bounds__(256) void attn_kernel(const bf16_t* __restrict__ q_ws,
                                                   const bf16_t* __restrict__ k_ws,
                                                   const bf16_t* __restrict__ v_ws,
                                                   bf16_t* __restrict__ ctx) {
    __shared__ __align__(16) bf16_t P[4][16][32];

    const int tid = threadIdx.x;
    const int w = tid >> 6;
    const int lane = tid & 63;
    const int lr = lane & 15;
    const int quad = lane >> 4;
    const int bh = blockIdx.x >> 5;
    const int qt = blockIdx.x & 31;
    const int t0 = qt * 64;
    const int trow = t0 + w * 16;

    const bf16_t* qb = q_ws + ((size_t)bh * 2048 + trow + lr) * 64 + quad * 8;
    const bf16x8 qlo = *(const bf16x8*)qb;
    const bf16x8 qhi = *(const bf16x8*)(qb + 32);

    f32x4 o0 = {}, o1 = {}, o2 = {}, o3 = {};
    float mrun[4], lrun[4];
#pragma unroll
    for (int r = 0; r < 4; r++) { mrun[r] = -1e9f; lrun[r] = 0.0f; }

    const int nkb = (t0 + 64) >> 5;
    for (int kb = 0; kb < nkb; kb++) {
        const int u0 = kb * 32;
        const bf16_t* kp = k_ws + ((size_t)bh * 2048 + u0 + lr) * 64 + quad * 8;
        const bf16x8 k0lo = *(const bf16x8*)kp;
        const bf16x8 k0hi = *(const bf16x8*)(kp + 32);
        const bf16x8 k1lo = *(const bf16x8*)(kp + 16 * 64);
        const bf16x8 k1hi = *(const bf16x8*)(kp + 16 * 64 + 32);

        const f32x4 z = {};
        f32x4 s0 = MFMA16(qlo, k0lo, z);
        s0 = MFMA16(qhi, k0hi, s0);
        f32x4 s1 = MFMA16(qlo, k1lo, z);
        s1 = MFMA16(qhi, k1hi, s1);

#pragma unroll
        for (int r = 0; r < 4; r++) {
            const int row = trow + quad * 4 + r;
            if (u0 + lr > row) s0[r] = -1e9f;
            if (u0 + 16 + lr > row) s1[r] = -1e9f;

            float tm = fmaxf(s0[r], s1[r]);
#pragma unroll
            for (int off = 8; off >= 1; off >>= 1)
                tm = fmaxf(tm, __shfl_xor(tm, off));
            const float mn = fmaxf(mrun[r], tm);
            const float al = __expf(mrun[r] - mn);

            const float p0 = __expf(s0[r] - mn);
            const float p1 = __expf(s1[r] - mn);
            float rs = p0 + p1;
#pragma unroll
            for (int off = 8; off >= 1; off >>= 1)
                rs += __shfl_xor(rs, off);

            lrun[r] = lrun[r] * al + rs;
            mrun[r] = mn;
            o0[r] *= al; o1[r] *= al; o2[r] *= al; o3[r] *= al;
            P[w][quad * 4 + r][lr] = (bf16_t)p0;
            P[w][quad * 4 + r][16 + lr] = (bf16_t)p1;
        }
        __syncthreads();

        const bf16x8 pf = *(const bf16x8*)&P[w][lr][quad * 8];
        const bf16_t* vp = v_ws + ((size_t)bh * 64 + lr) * 2048 + u0 + quad * 8;
        const bf16x8 v0 = *(const bf16x8*)vp;
        const bf16x8 v1 = *(const bf16x8*)(vp + 16 * 2048);
        const bf16x8 v2 = *(const bf16x8*)(vp + 32 * 2048);
        const bf16x8 v3 = *(const bf16x8*)(vp + 48 * 2048);
        o0 = MFMA16(pf, v0, o0);
        o1 = MFMA16(pf, v1, o1);
        o2 = MFMA16(pf, v2, o2);
        o3 = MFMA16(pf, v3, o3);
        __syncthreads();
    }

    const int b = bh >> 4;
    const int h = bh & 15;
#pragma unroll
    for (int r = 0; r < 4; r++) {
        const float inv = 1.0f / fmaxf(lrun[r], 1e-30f);
        const int row = trow + quad * 4 + r;
        const size_t base = ((size_t)b * 2048 + row) * 1024 + h * 64 + lr;
        ctx[base] = (bf16_t)(o0[r] * inv);
        ctx[base + 16] = (bf16_t)(o1[r] * inv);
        ctx[base + 32] = (bf16_t)(o2[r] * inv);
        ctx[base + 48] = (bf16_t)(o3[r] * inv);
    }
}

// ---------------------------------------------------------------------------
// Launcher. ws layout (bytes): flag[0,4) | q_ws@4K | k_ws@4K+8M | v_ws@4K+16M
//                              | ctx@4K+24M   (total 32M + 4K)
// ---------------------------------------------------------------------------
extern "C" void kernel_launch(void* const* d_in, const int* in_sizes, int n_in,
                              void* d_out, int out_size, void* d_ws, size_t ws_size,
                              hipStream_t stream) {
    const void* hs = d_in[0];
    const void* cosb = d_in[1];
    const void* sinb = d_in[2];
    const void* wqkv = d_in[3];
    const void* wo = d_in[4];

    char* ws = (char*)d_ws;
    int* flag = (int*)ws;
    bf16_t* q_ws = (bf16_t*)(ws + 4096);
    bf16_t* k_ws = (bf16_t*)(ws + 4096 + (size_t)(8u << 20));
    bf16_t* v_ws = (bf16_t*)(ws + 4096 + (size_t)(16u << 20));
    bf16_t* ctx = (bf16_t*)(ws + 4096 + (size_t)(24u << 20));

    const dim3 blk(256);

    // 0) dtype probe -> flag
    dtype_probe<<<dim3(1), dim3(64), 0, stream>>>((const unsigned short*)hs, flag);

    // 1) QKV projection + scatter:  M=4096, N=3072, K=1024
    gemm_bt<1, 3072, false><<<dim3(24, 32), blk, 0, stream>>>(
        hs, wqkv, nullptr, q_ws, k_ws, v_ws, flag);

    // 2) RoPE in place on q, k (+ fold 1/sqrt(D) into q)
    rope_kernel<<<dim3(16384), blk, 0, stream>>>(q_ws, k_ws, cosb, sinb, flag);

    // 3) Flash attention -> ctx [B,T,1024] (bf16)
    attn_kernel<<<dim3(1024), blk, 0, stream>>>(q_ws, k_ws, v_ws, ctx);

    // 4) Output projection: M=4096, N=1024, K=1024 (A = ctx always bf16)
    gemm_bt<0, 1024, true><<<dim3(8, 32), blk, 0, stream>>>(
        ctx, wo, d_out, nullptr, nullptr, nullptr, flag);
}

// Round 6
// 395.816 us; speedup vs baseline: 1.0860x; 1.0860x over previous
//
#include <hip/hip_runtime.h>

typedef __bf16 bf16_t;
typedef __bf16 bf16x4 __attribute__((ext_vector_type(4)));
typedef __bf16 bf16x8 __attribute__((ext_vector_type(8)));
typedef float f32x4 __attribute__((ext_vector_type(4)));

#define MFMA16(a, b, c) __builtin_amdgcn_mfma_f32_16x16x32_bf16((a), (b), (c), 0, 0, 0)

// load 8 consecutive elements as bf16x8 (fp32 source converted)
__device__ inline bf16x8 load8(const float* p) {
    const f32x4 a = *(const f32x4*)p;
    const f32x4 b = *(const f32x4*)(p + 4);
    bf16x8 r;
#pragma unroll
    for (int i = 0; i < 4; i++) { r[i] = (bf16_t)a[i]; r[4 + i] = (bf16_t)b[i]; }
    return r;
}
__device__ inline bf16x8 load8(const bf16_t* p) { return *(const bf16x8*)p; }

// ---------------------------------------------------------------------------
// GEMM: C[M x N] = A[M x K] * B[N x K]^T,  K = 1024, fp32 (or bf16 ws) inputs.
// 128x128 tile, BK=32, 256 threads (4 waves), wave = 64x64 = 4x4 MFMA tiles.
// MODE 0: store C row-major fp32 to outp (N = NDIM)
// MODE 1: qkv scatter: j<16 -> q_ws[bh][t][d]; j<32 -> k_ws; else v_ws[bh][d][t]
// ---------------------------------------------------------------------------
template <int MODE, int NDIM, typename TA>
__global__ __launch_bounds__(256) void gemm_bt(const TA* __restrict__ A,
                                               const float* __restrict__ B,
                                               float* __restrict__ outp,
                                               bf16_t* __restrict__ q_ws,
                                               bf16_t* __restrict__ k_ws,
                                               bf16_t* __restrict__ v_ws) {
    constexpr int K = 1024;
    __shared__ __align__(16) bf16_t As[128 * 32];
    __shared__ __align__(16) bf16_t Bs[128 * 32];

    const int tid = threadIdx.x;
    const int w = tid >> 6;
    const int lane = tid & 63;
    const int lr = lane & 15;
    const int quad = lane >> 4;
    const int m0 = blockIdx.y * 128;
    const int n0 = blockIdx.x * 128;
    const int wm = (w & 1) * 64;
    const int wn = (w >> 1) * 64;

    const int srow = tid >> 2;
    const int skk = (tid & 3) * 8;
    const TA* gA0 = A + (size_t)(m0 + srow) * K + skk;
    const TA* gA1 = gA0 + (size_t)64 * K;
    const float* gB0 = B + (size_t)(n0 + srow) * K + skk;
    const float* gB1 = gB0 + (size_t)64 * K;

    f32x4 acc[4][4] = {};

    for (int k0 = 0; k0 < K; k0 += 32) {
        const bf16x8 ra0 = load8(gA0 + k0);
        const bf16x8 ra1 = load8(gA1 + k0);
        const bf16x8 rb0 = load8(gB0 + k0);
        const bf16x8 rb1 = load8(gB1 + k0);
        __syncthreads();  // previous iteration done reading LDS
        *(bf16x8*)&As[srow * 32 + skk] = ra0;
        *(bf16x8*)&As[(64 + srow) * 32 + skk] = ra1;
        *(bf16x8*)&Bs[srow * 32 + skk] = rb0;
        *(bf16x8*)&Bs[(64 + srow) * 32 + skk] = rb1;
        __syncthreads();  // LDS tile ready

        bf16x8 af[4], bfm[4];
#pragma unroll
        for (int im = 0; im < 4; im++)
            af[im] = *(const bf16x8*)&As[(wm + im * 16 + lr) * 32 + quad * 8];
#pragma unroll
        for (int in = 0; in < 4; in++)
            bfm[in] = *(const bf16x8*)&Bs[(wn + in * 16 + lr) * 32 + quad * 8];
#pragma unroll
        for (int im = 0; im < 4; im++)
#pragma unroll
            for (int in = 0; in < 4; in++)
                acc[im][in] = MFMA16(af[im], bfm[in], acc[im][in]);
    }

#pragma unroll
    for (int im = 0; im < 4; im++) {
#pragma unroll
        for (int in = 0; in < 4; in++) {
#pragma unroll
            for (int r = 0; r < 4; r++) {
                const int m = m0 + wm + im * 16 + quad * 4 + r;
                const int n = n0 + wn + in * 16 + lr;
                const float v = acc[im][in][r];
                if constexpr (MODE == 0) {
                    outp[(size_t)m * NDIM + n] = v;
                } else {
                    const int b = m >> 11;      // T = 2048
                    const int t = m & 2047;
                    const int j = n >> 6;       // which of 48 head-slots
                    const int d = n & 63;
                    if (j < 16) {
                        q_ws[(((size_t)(b * 16 + j) * 2048) + t) * 64 + d] = (bf16_t)v;
                    } else if (j < 32) {
                        k_ws[(((size_t)(b * 16 + (j - 16)) * 2048) + t) * 64 + d] = (bf16_t)v;
                    } else {
                        v_ws[((size_t)(b * 16 + (j - 32)) * 64 + d) * 2048 + t] = (bf16_t)v;
                    }
                }
            }
        }
    }
}

// ---------------------------------------------------------------------------
// RoPE in place on q_ws, k_ws ([bh][t][64] bf16). Pairs (d, d+32).
// Folds 0.125 * log2(e) into q so attention can use exp2.
// idx bits: d[0:5) t[5:16) bh[16:21) isk[21]
// ---------------------------------------------------------------------------
__global__ __launch_bounds__(256) void rope_kernel(bf16_t* __restrict__ q_ws,
                                                   bf16_t* __restrict__ k_ws,
                                                   const float* __restrict__ cosb,
                                                   const float* __restrict__ sinb) {
    const int idx = blockIdx.x * 256 + threadIdx.x;
    const int d = idx & 31;
    const int t = (idx >> 5) & 2047;
    const int bh = (idx >> 16) & 31;
    const int isk = idx >> 21;
    bf16_t* p = isk ? k_ws : q_ws;
    const size_t base = ((size_t)bh * 2048 + t) * 64;
    const float x1 = (float)p[base + d];
    const float x2 = (float)p[base + d + 32];
    const float c = cosb[t * 64 + d];
    const float s = sinb[t * 64 + d];
    float y1 = x1 * c - x2 * s;
    float y2 = x2 * c + x1 * s;
    if (!isk) {
        const float qs = 0.125f * 1.44269504089f;  // fold log2(e): attn uses exp2
        y1 *= qs; y2 *= qs;
    }
    p[base + d] = (bf16_t)y1;
    p[base + d + 32] = (bf16_t)y2;
}

// ---------------------------------------------------------------------------
// Flash attention, transposed-score formulation. Grid: bh(32) x qtile(32),
// 256 threads = 4 waves; wave w owns Q rows [t0+16w, t0+16w+16).
// Per lane: one query column (lr), keys on quads.
//   S' = K Q^T  (C-layout: row=key=quad*4+r, col=query=lr)
//   softmax: local 8-val reduce + shfl_xor(16,32); m/l scalar per lane
//   P' -> LDS transpose guarded by double __syncthreads (uniform trip count:
//   ALL waves run nkb = 2(qt+1) blocks; beyond-diagonal blocks fully masked
//   -> contribute exactly 0, keeps barriers legal and scheduling fenced)
//   O^T = V^T P' (A = v_ws[bh][d][t] direct 16B loads)
// ---------------------------------------------------------------------------
__global__ __launch_bounds__(256) void attn_kernel(const bf16_t* __restrict__ q_ws,
                                                   const bf16_t* __restrict__ k_ws,
                                                   const bf16_t* __restrict__ v_ws,
                                                   bf16_t* __restrict__ ctx) {
    __shared__ __align__(16) bf16_t P[4][16][32];

    const int tid = threadIdx.x;
    const int w = tid >> 6;
    const int lane = tid & 63;
    const int lr = lane & 15;
    const int quad = lane >> 4;
    const int bh = blockIdx.x >> 5;
    const int qt = blockIdx.x & 31;
    const int trow = qt * 64 + w * 16;
    const int query = trow + lr;

    const bf16_t* qb = q_ws + ((size_t)bh * 2048 + trow + lr) * 64 + quad * 8;
    const bf16x8 qlo = *(const bf16x8*)qb;
    const bf16x8 qhi = *(const bf16x8*)(qb + 32);

    const bf16_t* kbase = k_ws + (size_t)bh * 2048 * 64;
    const bf16_t* vbase = v_ws + (size_t)bh * 64 * 2048;

    f32x4 o0 = {}, o1 = {}, o2 = {}, o3 = {};
    float mrun = -1e9f, lrun = 0.0f;

    const int nfull = trow >> 5;   // first block needing a mask (per wave)
    const int nkb = (qt + 1) * 2;  // uniform trip count across all 4 waves
    for (int kb = 0; kb < nkb; kb++) {
        const int u0 = kb * 32;
        const bf16_t* kp = kbase + (size_t)(u0 + lr) * 64 + quad * 8;
        const bf16x8 k0lo = *(const bf16x8*)kp;
        const bf16x8 k0hi = *(const bf16x8*)(kp + 32);
        const bf16x8 k1lo = *(const bf16x8*)(kp + 16 * 64);
        const bf16x8 k1hi = *(const bf16x8*)(kp + 16 * 64 + 32);

        const f32x4 z = {};
        f32x4 s0 = MFMA16(k0lo, qlo, z);
        s0 = MFMA16(k0hi, qhi, s0);
        f32x4 s1 = MFMA16(k1lo, qlo, z);
        s1 = MFMA16(k1hi, qhi, s1);

        if (kb >= nfull) {  // diagonal & beyond: causal mask (key > query)
#pragma unroll
            for (int r = 0; r < 4; r++) {
                if (u0 + quad * 4 + r > query) s0[r] = -1e9f;
                if (u0 + 16 + quad * 4 + r > query) s1[r] = -1e9f;
            }
        }

        float tm = fmaxf(fmaxf(fmaxf(s0[0], s0[1]), fmaxf(s0[2], s0[3])),
                         fmaxf(fmaxf(s1[0], s1[1]), fmaxf(s1[2], s1[3])));
        tm = fmaxf(tm, __shfl_xor(tm, 16));
        tm = fmaxf(tm, __shfl_xor(tm, 32));
        const float mn = fmaxf(mrun, tm);
        const float al = exp2f(mrun - mn);

        f32x4 p0, p1;
#pragma unroll
        for (int r = 0; r < 4; r++) {
            p0[r] = exp2f(s0[r] - mn);
            p1[r] = exp2f(s1[r] - mn);
        }
        float rs = ((p0[0] + p0[1]) + (p0[2] + p0[3])) +
                   ((p1[0] + p1[1]) + (p1[2] + p1[3]));
        rs += __shfl_xor(rs, 16);
        rs += __shfl_xor(rs, 32);
        lrun = lrun * al + rs;
        mrun = mn;
        o0 *= al; o1 *= al; o2 *= al; o3 *= al;

        bf16x4 pb0, pb1;
#pragma unroll
        for (int r = 0; r < 4; r++) { pb0[r] = (bf16_t)p0[r]; pb1[r] = (bf16_t)p1[r]; }

        __syncthreads();  // everyone done reading P from previous block
        *(bf16x4*)&P[w][lr][quad * 4] = pb0;        // P[w][query][key]
        *(bf16x4*)&P[w][lr][16 + quad * 4] = pb1;
        __syncthreads();  // P transpose visible
        const bf16x8 pf = *(const bf16x8*)&P[w][lr][quad * 8];

        const bf16_t* vp = vbase + (size_t)lr * 2048 + u0 + quad * 8;
        const bf16x8 v0 = *(const bf16x8*)vp;
        const bf16x8 v1 = *(const bf16x8*)(vp + 16 * 2048);
        const bf16x8 v2 = *(const bf16x8*)(vp + 32 * 2048);
        const bf16x8 v3 = *(const bf16x8*)(vp + 48 * 2048);
        o0 = MFMA16(v0, pf, o0);
        o1 = MFMA16(v1, pf, o1);
        o2 = MFMA16(v2, pf, o2);
        o3 = MFMA16(v3, pf, o3);
    }

    // epilogue: lane owns query=trow+lr, d = im*16 + quad*4 + r
    const int b = bh >> 4;
    const int h = bh & 15;
    const float inv = 1.0f / fmaxf(lrun, 1e-30f);
    const size_t base = ((size_t)b * 2048 + query) * 1024 + h * 64 + quad * 4;
    f32x4 oo[4] = {o0, o1, o2, o3};
#pragma unroll
    for (int im = 0; im < 4; im++) {
        bf16x4 ob;
#pragma unroll
        for (int r = 0; r < 4; r++) ob[r] = (bf16_t)(oo[im][r] * inv);
        *(bf16x4*)&ctx[base + im * 16] = ob;
    }
}

// ---------------------------------------------------------------------------
// Launcher. Inputs fp32, output fp32. ws: q_ws[0,8M) k_ws[8M,16M) v_ws[16M,24M)
// ctx[24M,32M)
// ---------------------------------------------------------------------------
extern "C" void kernel_launch(void* const* d_in, const int* in_sizes, int n_in,
                              void* d_out, int out_size, void* d_ws, size_t ws_size,
                              hipStream_t stream) {
    const float* hs = (const float*)d_in[0];
    const float* cosb = (const float*)d_in[1];
    const float* sinb = (const float*)d_in[2];
    const float* wqkv = (const float*)d_in[3];
    const float* wo = (const float*)d_in[4];
    float* out = (float*)d_out;

    char* ws = (char*)d_ws;
    bf16_t* q_ws = (bf16_t*)(ws);
    bf16_t* k_ws = (bf16_t*)(ws + (size_t)(8u << 20));
    bf16_t* v_ws = (bf16_t*)(ws + (size_t)(16u << 20));
    bf16_t* ctx = (bf16_t*)(ws + (size_t)(24u << 20));

    const dim3 blk(256);

    // 1) QKV projection + scatter:  M=4096, N=3072, K=1024
    gemm_bt<1, 3072><<<dim3(24, 32), blk, 0, stream>>>(hs, wqkv, nullptr,
                                                       q_ws, k_ws, v_ws);

    // 2) RoPE in place on q, k (+ fold scale*log2e into q)
    rope_kernel<<<dim3(16384), blk, 0, stream>>>(q_ws, k_ws, cosb, sinb);

    // 3) Flash attention -> ctx [B,T,1024] (bf16)
    attn_kernel<<<dim3(1024), blk, 0, stream>>>(q_ws, k_ws, v_ws, ctx);

    // 4) Output projection: M=4096, N=1024, K=1024 (A = ctx bf16)
    gemm_bt<0, 1024><<<dim3(8, 32), blk, 0, stream>>>(ctx, wo, out,
                                                      nullptr, nullptr, nullptr);
}

// Round 7
// 313.029 us; speedup vs baseline: 1.3732x; 1.2645x over previous
//
#include <hip/hip_runtime.h>

typedef __bf16 bf16_t;
typedef __bf16 bf16x4 __attribute__((ext_vector_type(4)));
typedef __bf16 bf16x8 __attribute__((ext_vector_type(8)));
typedef float f32x4 __attribute__((ext_vector_type(4)));
typedef unsigned long long u64;

#define MFMA16(a, b, c) __builtin_amdgcn_mfma_f32_16x16x32_bf16((a), (b), (c), 0, 0, 0)

// load 8 consecutive elements as bf16x8 (fp32 source converted)
__device__ inline bf16x8 load8(const float* p) {
    const f32x4 a = *(const f32x4*)p;
    const f32x4 b = *(const f32x4*)(p + 4);
    bf16x8 r;
#pragma unroll
    for (int i = 0; i < 4; i++) { r[i] = (bf16_t)a[i]; r[4 + i] = (bf16_t)b[i]; }
    return r;
}
__device__ inline bf16x8 load8(const bf16_t* p) { return *(const bf16x8*)p; }

// 8-byte cross-lane shuffle of a packed bf16x4
__device__ inline bf16x4 shfl4(bf16x4 v, int src) {
    u64 x;
    __builtin_memcpy(&x, &v, 8);
    x = __shfl(x, src, 64);
    bf16x4 r;
    __builtin_memcpy(&r, &x, 8);
    return r;
}

// ---------------------------------------------------------------------------
// GEMM: C[M x N] = A[M x K] * B[N x K]^T,  K = 1024, fp32 (or bf16 ws) inputs.
// 128x128 tile, BK=32, 256 threads (4 waves), wave = 64x64 = 4x4 MFMA tiles.
// MODE 0: store C row-major fp32 to outp (N = NDIM)
// MODE 1: qkv scatter: j<16 -> q_ws[bh][t][d]; j<32 -> k_ws; else v_ws[bh][d][t]
// ---------------------------------------------------------------------------
template <int MODE, int NDIM, typename TA>
__global__ __launch_bounds__(256) void gemm_bt(const TA* __restrict__ A,
                                               const float* __restrict__ B,
                                               float* __restrict__ outp,
                                               bf16_t* __restrict__ q_ws,
                                               bf16_t* __restrict__ k_ws,
                                               bf16_t* __restrict__ v_ws) {
    constexpr int K = 1024;
    __shared__ __align__(16) bf16_t As[128 * 32];
    __shared__ __align__(16) bf16_t Bs[128 * 32];

    const int tid = threadIdx.x;
    const int w = tid >> 6;
    const int lane = tid & 63;
    const int lr = lane & 15;
    const int quad = lane >> 4;
    const int m0 = blockIdx.y * 128;
    const int n0 = blockIdx.x * 128;
    const int wm = (w & 1) * 64;
    const int wn = (w >> 1) * 64;

    const int srow = tid >> 2;
    const int skk = (tid & 3) * 8;
    const TA* gA0 = A + (size_t)(m0 + srow) * K + skk;
    const TA* gA1 = gA0 + (size_t)64 * K;
    const float* gB0 = B + (size_t)(n0 + srow) * K + skk;
    const float* gB1 = gB0 + (size_t)64 * K;

    f32x4 acc[4][4] = {};

    for (int k0 = 0; k0 < K; k0 += 32) {
        const bf16x8 ra0 = load8(gA0 + k0);
        const bf16x8 ra1 = load8(gA1 + k0);
        const bf16x8 rb0 = load8(gB0 + k0);
        const bf16x8 rb1 = load8(gB1 + k0);
        __syncthreads();  // previous iteration done reading LDS
        *(bf16x8*)&As[srow * 32 + skk] = ra0;
        *(bf16x8*)&As[(64 + srow) * 32 + skk] = ra1;
        *(bf16x8*)&Bs[srow * 32 + skk] = rb0;
        *(bf16x8*)&Bs[(64 + srow) * 32 + skk] = rb1;
        __syncthreads();  // LDS tile ready

        bf16x8 af[4], bfm[4];
#pragma unroll
        for (int im = 0; im < 4; im++)
            af[im] = *(const bf16x8*)&As[(wm + im * 16 + lr) * 32 + quad * 8];
#pragma unroll
        for (int in = 0; in < 4; in++)
            bfm[in] = *(const bf16x8*)&Bs[(wn + in * 16 + lr) * 32 + quad * 8];
#pragma unroll
        for (int im = 0; im < 4; im++)
#pragma unroll
            for (int in = 0; in < 4; in++)
                acc[im][in] = MFMA16(af[im], bfm[in], acc[im][in]);
    }

#pragma unroll
    for (int im = 0; im < 4; im++) {
#pragma unroll
        for (int in = 0; in < 4; in++) {
#pragma unroll
            for (int r = 0; r < 4; r++) {
                const int m = m0 + wm + im * 16 + quad * 4 + r;
                const int n = n0 + wn + in * 16 + lr;
                const float v = acc[im][in][r];
                if constexpr (MODE == 0) {
                    outp[(size_t)m * NDIM + n] = v;
                } else {
                    const int b = m >> 11;      // T = 2048
                    const int t = m & 2047;
                    const int j = n >> 6;       // which of 48 head-slots
                    const int d = n & 63;
                    if (j < 16) {
                        q_ws[(((size_t)(b * 16 + j) * 2048) + t) * 64 + d] = (bf16_t)v;
                    } else if (j < 32) {
                        k_ws[(((size_t)(b * 16 + (j - 16)) * 2048) + t) * 64 + d] = (bf16_t)v;
                    } else {
                        v_ws[((size_t)(b * 16 + (j - 32)) * 64 + d) * 2048 + t] = (bf16_t)v;
                    }
                }
            }
        }
    }
}

// ---------------------------------------------------------------------------
// RoPE in place on q_ws, k_ws ([bh][t][64] bf16). Pairs (d, d+32).
// Folds 0.125 * log2(e) into q so attention can use exp2.
// idx bits: d[0:5) t[5:16) bh[16:21) isk[21]
// ---------------------------------------------------------------------------
__global__ __launch_bounds__(256) void rope_kernel(bf16_t* __restrict__ q_ws,
                                                   bf16_t* __restrict__ k_ws,
                                                   const float* __restrict__ cosb,
                                                   const float* __restrict__ sinb) {
    const int idx = blockIdx.x * 256 + threadIdx.x;
    const int d = idx & 31;
    const int t = (idx >> 5) & 2047;
    const int bh = (idx >> 16) & 31;
    const int isk = idx >> 21;
    bf16_t* p = isk ? k_ws : q_ws;
    const size_t base = ((size_t)bh * 2048 + t) * 64;
    const float x1 = (float)p[base + d];
    const float x2 = (float)p[base + d + 32];
    const float c = cosb[t * 64 + d];
    const float s = sinb[t * 64 + d];
    float y1 = x1 * c - x2 * s;
    float y2 = x2 * c + x1 * s;
    if (!isk) {
        const float qs = 0.125f * 1.44269504089f;  // fold log2(e): attn uses exp2
        y1 *= qs; y2 *= qs;
    }
    p[base + d] = (bf16_t)y1;
    p[base + d + 32] = (bf16_t)y2;
}

// ---------------------------------------------------------------------------
// Flash attention, transposed-score, barrier-free, LDS-free.
// Grid: blockIdx.x = qt*32 + bh  (qt-major: balances per-CU work since CU
// stride 256 ≡ 0 mod 32 -> co-resident WGs get qt {x,x+8,x+16,x+24}; each XCD
// sees only 4 heads' K/V = 2MB, L2-resident).
// 4 independent waves; wave w owns queries [qt*64+16w, +16). Per 64-key block:
//   S' = K Q^T (4 subtiles; C-layout row=key=quad*4+r, col=query=lr)
//   per-lane softmax: local 16-val reduce + shfl_xor(16,32)
//   P C-layout -> PV B-layout via pure lane permutation (4x 8B shfl per half):
//     dest(quad,lr) low4  = pb[quad<2 ? loKeys : hiKeys] of lane (quad&1)*32+lr
//     dest(quad,lr) high4 = same of lane (quad&1)*32+16+lr
//   O^T = V^T P' (v_ws[bh][d][t] 16B loads)
// ---------------------------------------------------------------------------
__global__ __launch_bounds__(256) void attn_kernel(const bf16_t* __restrict__ q_ws,
                                                   const bf16_t* __restrict__ k_ws,
                                                   const bf16_t* __restrict__ v_ws,
                                                   bf16_t* __restrict__ ctx) {
    const int tid = threadIdx.x;
    const int w = tid >> 6;
    const int lane = tid & 63;
    const int lr = lane & 15;
    const int quad = lane >> 4;
    const int bh = blockIdx.x & 31;
    const int qt = blockIdx.x >> 5;
    const int trow = qt * 64 + w * 16;
    const int query = trow + lr;

    const bf16_t* qb = q_ws + ((size_t)bh * 2048 + trow + lr) * 64 + quad * 8;
    const bf16x8 qlo = *(const bf16x8*)qb;
    const bf16x8 qhi = *(const bf16x8*)(qb + 32);

    const bf16_t* kbase = k_ws + (size_t)bh * 2048 * 64;
    const bf16_t* vbase = v_ws + (size_t)bh * 64 * 2048;

    f32x4 o0 = {}, o1 = {}, o2 = {}, o3 = {};
    float mrun = -1e9f, lrun = 0.0f;

    const int srcLow = ((quad & 1) << 5) + lr;
    const int srcHigh = srcLow + 16;
    const bool loSel = (quad < 2);

    for (int kb = 0; kb <= qt; kb++) {
        const int u0 = kb * 64;
        const bf16_t* kp = kbase + (size_t)(u0 + lr) * 64 + quad * 8;

        f32x4 s[4];
#pragma unroll
        for (int n = 0; n < 4; n++) {
            const bf16x8 klo = *(const bf16x8*)(kp + n * 16 * 64);
            const bf16x8 khi = *(const bf16x8*)(kp + n * 16 * 64 + 32);
            const f32x4 z = {};
            s[n] = MFMA16(klo, qlo, z);
            s[n] = MFMA16(khi, qhi, s[n]);
        }

        if (kb == qt) {  // diagonal 64-key block: causal mask (key > query)
#pragma unroll
            for (int n = 0; n < 4; n++)
#pragma unroll
                for (int r = 0; r < 4; r++)
                    if (u0 + n * 16 + quad * 4 + r > query) s[n][r] = -1e9f;
        }

        float tm = -1e9f;
#pragma unroll
        for (int n = 0; n < 4; n++)
#pragma unroll
            for (int r = 0; r < 4; r++) tm = fmaxf(tm, s[n][r]);
        tm = fmaxf(tm, __shfl_xor(tm, 16));
        tm = fmaxf(tm, __shfl_xor(tm, 32));
        const float mn = fmaxf(mrun, tm);
        const float al = exp2f(mrun - mn);

        f32x4 p[4];
        float rs = 0.0f;
#pragma unroll
        for (int n = 0; n < 4; n++) {
#pragma unroll
            for (int r = 0; r < 4; r++) {
                p[n][r] = exp2f(s[n][r] - mn);
                rs += p[n][r];
            }
        }
        rs += __shfl_xor(rs, 16);
        rs += __shfl_xor(rs, 32);
        lrun = lrun * al + rs;
        mrun = mn;
        o0 *= al; o1 *= al; o2 *= al; o3 *= al;

        bf16x4 pb[4];
#pragma unroll
        for (int n = 0; n < 4; n++)
#pragma unroll
            for (int r = 0; r < 4; r++) pb[n][r] = (bf16_t)p[n][r];

#pragma unroll
        for (int hh = 0; hh < 2; hh++) {  // 32-key halves
            const bf16x4 a0 = shfl4(pb[2 * hh], srcLow);
            const bf16x4 a1 = shfl4(pb[2 * hh + 1], srcLow);
            const bf16x4 b0 = shfl4(pb[2 * hh], srcHigh);
            const bf16x4 b1 = shfl4(pb[2 * hh + 1], srcHigh);
            const bf16x4 lo = loSel ? a0 : a1;
            const bf16x4 hi = loSel ? b0 : b1;
            bf16x8 pf;
#pragma unroll
            for (int r = 0; r < 4; r++) { pf[r] = lo[r]; pf[4 + r] = hi[r]; }

            const bf16_t* vp = vbase + (size_t)lr * 2048 + u0 + hh * 32 + quad * 8;
            o0 = MFMA16(*(const bf16x8*)vp, pf, o0);
            o1 = MFMA16(*(const bf16x8*)(vp + 16 * 2048), pf, o1);
            o2 = MFMA16(*(const bf16x8*)(vp + 32 * 2048), pf, o2);
            o3 = MFMA16(*(const bf16x8*)(vp + 48 * 2048), pf, o3);
        }
    }

    // epilogue: lane owns query=trow+lr, d = im*16 + quad*4 + r
    const int b = bh >> 4;
    const int hd = bh & 15;
    const float inv = 1.0f / fmaxf(lrun, 1e-30f);
    const size_t base = ((size_t)b * 2048 + query) * 1024 + hd * 64 + quad * 4;
    f32x4 oo[4] = {o0, o1, o2, o3};
#pragma unroll
    for (int im = 0; im < 4; im++) {
        bf16x4 ob;
#pragma unroll
        for (int r = 0; r < 4; r++) ob[r] = (bf16_t)(oo[im][r] * inv);
        *(bf16x4*)&ctx[base + im * 16] = ob;
    }
}

// ---------------------------------------------------------------------------
// Launcher. Inputs fp32, output fp32. ws: q_ws[0,8M) k_ws[8M,16M) v_ws[16M,24M)
// ctx[24M,32M)
// ---------------------------------------------------------------------------
extern "C" void kernel_launch(void* const* d_in, const int* in_sizes, int n_in,
                              void* d_out, int out_size, void* d_ws, size_t ws_size,
                              hipStream_t stream) {
    const float* hs = (const float*)d_in[0];
    const float* cosb = (const float*)d_in[1];
    const float* sinb = (const float*)d_in[2];
    const float* wqkv = (const float*)d_in[3];
    const float* wo = (const float*)d_in[4];
    float* out = (float*)d_out;

    char* ws = (char*)d_ws;
    bf16_t* q_ws = (bf16_t*)(ws);
    bf16_t* k_ws = (bf16_t*)(ws + (size_t)(8u << 20));
    bf16_t* v_ws = (bf16_t*)(ws + (size_t)(16u << 20));
    bf16_t* ctx = (bf16_t*)(ws + (size_t)(24u << 20));

    const dim3 blk(256);

    // 1) QKV projection + scatter:  M=4096, N=3072, K=1024
    gemm_bt<1, 3072><<<dim3(24, 32), blk, 0, stream>>>(hs, wqkv, nullptr,
                                                       q_ws, k_ws, v_ws);

    // 2) RoPE in place on q, k (+ fold scale*log2e into q)
    rope_kernel<<<dim3(16384), blk, 0, stream>>>(q_ws, k_ws, cosb, sinb);

    // 3) Flash attention -> ctx [B,T,1024] (bf16)
    attn_kernel<<<dim3(1024), blk, 0, stream>>>(q_ws, k_ws, v_ws, ctx);

    // 4) Output projection: M=4096, N=1024, K=1024 (A = ctx bf16)
    gemm_bt<0, 1024><<<dim3(8, 32), blk, 0, stream>>>(ctx, wo, out,
                                                      nullptr, nullptr, nullptr);
}